// Round 15
// baseline (1346.805 us; speedup 1.0000x reference)
//
#include <hip/hip_runtime.h>
#include <math.h>

#define NN 100000
#define NE 400000
#define HID 128
#define HEADS 4
#define NG 2000
#define BN_EPS 1e-5f
#define NEG_SLOPE 0.2f
#define NB_SCAN 391   // cdiv(NN,256)

__global__ void k_zero_i(int* __restrict__ p, int n) {
    int i = blockIdx.x * blockDim.x + threadIdx.x;
    if (i < n) p[i] = 0;
}

__global__ void k_count(const int* __restrict__ dst, int* __restrict__ cnt) {
    int e = blockIdx.x * blockDim.x + threadIdx.x;
    if (e < NE) atomicAdd(&cnt[dst[e]], 1);
}

__global__ void k_dinv2(const int* __restrict__ cnt, float* __restrict__ dinv) {
    int n = blockIdx.x * blockDim.x + threadIdx.x;
    if (n < NN) dinv[n] = rsqrtf((float)cnt[n] + 1.0f);   // +1 self loop
}

__global__ __launch_bounds__(256) void k_bsum(const int* __restrict__ cnt, int* __restrict__ bsum) {
    __shared__ int s[256];
    int tid = threadIdx.x;
    int n = blockIdx.x * 256 + tid;
    s[tid] = (n < NN) ? cnt[n] : 0;
    __syncthreads();
    for (int off = 128; off > 0; off >>= 1) {
        if (tid < off) s[tid] += s[tid + off];
        __syncthreads();
    }
    if (tid == 0) bsum[blockIdx.x] = s[0];
}

// exclusive scan of bsum[NB_SCAN] in one block; also set row_ptr[NN]=NE
__global__ __launch_bounds__(512) void k_bscan(int* __restrict__ bsum, int* __restrict__ row_ptr) {
    __shared__ int s[512];
    int tid = threadIdx.x;
    int v = (tid < NB_SCAN) ? bsum[tid] : 0;
    s[tid] = v;
    __syncthreads();
    for (int off = 1; off < 512; off <<= 1) {
        int t_ = (tid >= off) ? s[tid - off] : 0;
        __syncthreads();
        s[tid] += t_;
        __syncthreads();
    }
    if (tid < NB_SCAN) bsum[tid] = s[tid] - v;   // exclusive block offsets
    if (tid == 0) row_ptr[NN] = NE;
}

__global__ __launch_bounds__(256) void k_rowptr(const int* __restrict__ cnt, const int* __restrict__ boff,
                                                int* __restrict__ row_ptr) {
    __shared__ int s[256];
    int tid = threadIdx.x;
    int n = blockIdx.x * 256 + tid;
    int v = (n < NN) ? cnt[n] : 0;
    s[tid] = v;
    __syncthreads();
    for (int off = 1; off < 256; off <<= 1) {
        int t_ = (tid >= off) ? s[tid - off] : 0;
        __syncthreads();
        s[tid] += t_;
        __syncthreads();
    }
    if (n < NN) row_ptr[n] = boff[blockIdx.x] + s[tid] - v;
}

__global__ void k_csr(const int* __restrict__ src, const int* __restrict__ dst,
                      const int* __restrict__ row_ptr, int* __restrict__ fill,
                      const float* __restrict__ dinv,
                      int* __restrict__ csr_src, float* __restrict__ csr_w) {
    int e = blockIdx.x * blockDim.x + threadIdx.x;
    if (e >= NE) return;
    int s = src[e], d = dst[e];
    int pos = row_ptr[d] + atomicAdd(&fill[d], 1);
    csr_src[pos] = s;
    csr_w[pos] = dinv[s] * dinv[d];
}

// C[r, c] = sum_k A[r,k] * W[k*ldw + coffW + c]; optional fused att-score epilogue.
// 128x128 tile per 512-thread block; K=128 in two 64-halves. LDS 64KB.
// Inner loop: k chunked by 4; As read as float4 (broadcast), Ws as float4.
__global__ __launch_bounds__(512) void k_gemm128(const float* __restrict__ A,
                                                 const float* __restrict__ W,
                                                 float* __restrict__ C,
                                                 int nrows, int ldw, int coffW,
                                                 const float* __restrict__ att_s,
                                                 const float* __restrict__ att_d,
                                                 float* __restrict__ as_out,
                                                 float* __restrict__ ad_out) {
    __shared__ float Ws[64][128];
    __shared__ float As[128][64];
    int tid = threadIdx.x;
    int row0 = blockIdx.x * 128;
    int c0 = (tid & 31) * 4;      // 4 consecutive output cols
    int r0 = (tid >> 5) * 8;      // 8 consecutive output rows
    float acc[8][4] = {};
    for (int kb = 0; kb < 2; ++kb) {
        __syncthreads();
        for (int i = tid; i < 2048; i += 512) {
            int k  = i >> 5;
            int c4 = (i & 31) * 4;
            *(float4*)&Ws[k][c4] =
                *(const float4*)&W[(long)(kb * 64 + k) * ldw + coffW + c4];
        }
        for (int i = tid; i < 2048; i += 512) {
            int r  = i >> 4;
            int k4 = (i & 15) * 4;
            int gr = row0 + r;
            float4 v = (gr < nrows)
                ? *(const float4*)&A[(long)gr * 128 + kb * 64 + k4]
                : make_float4(0.f, 0.f, 0.f, 0.f);
            *(float4*)&As[r][k4] = v;
        }
        __syncthreads();
        for (int k4 = 0; k4 < 64; k4 += 4) {
            float4 a4[8];
#pragma unroll
            for (int j = 0; j < 8; ++j) a4[j] = *(const float4*)&As[r0 + j][k4];
#pragma unroll
            for (int i = 0; i < 4; ++i) {
                float4 wv = *(const float4*)&Ws[k4 + i][c0];
#pragma unroll
                for (int j = 0; j < 8; ++j) {
                    float a = (i == 0) ? a4[j].x : (i == 1) ? a4[j].y : (i == 2) ? a4[j].z : a4[j].w;
                    acc[j][0] += a * wv.x;
                    acc[j][1] += a * wv.y;
                    acc[j][2] += a * wv.z;
                    acc[j][3] += a * wv.w;
                }
            }
        }
    }
#pragma unroll
    for (int j = 0; j < 8; ++j) {
        int gr = row0 + r0 + j;
        if (gr < nrows)
            *(float4*)&C[(long)gr * 128 + c0] =
                make_float4(acc[j][0], acc[j][1], acc[j][2], acc[j][3]);
    }
    if (att_s) {
        // per-row dot with att vectors; row r held by 32 consecutive lanes
#pragma unroll
        for (int j = 0; j < 8; ++j) {
            float ps = acc[j][0] * att_s[c0] + acc[j][1] * att_s[c0 + 1]
                     + acc[j][2] * att_s[c0 + 2] + acc[j][3] * att_s[c0 + 3];
            float pd = acc[j][0] * att_d[c0] + acc[j][1] * att_d[c0 + 1]
                     + acc[j][2] * att_d[c0 + 2] + acc[j][3] * att_d[c0 + 3];
#pragma unroll
            for (int off = 16; off > 0; off >>= 1) {
                ps += __shfl_down(ps, off, 32);
                pd += __shfl_down(pd, off, 32);
            }
            int gr = row0 + r0 + j;
            if ((tid & 31) == 0 && gr < nrows) { as_out[gr] = ps; ad_out[gr] = pd; }
        }
    }
}

// fused CSR gather + bias + BN + ReLU + residual (no atomics)
__global__ __launch_bounds__(128) void k_gcn_agg(const float* __restrict__ t,
                                                 const int* __restrict__ row_ptr,
                                                 const int* __restrict__ csr_src,
                                                 const float* __restrict__ csr_w,
                                                 const float* __restrict__ dinv,
                                                 const float* __restrict__ b,
                                                 const float* __restrict__ gamma,
                                                 const float* __restrict__ beta,
                                                 const float* __restrict__ mean,
                                                 const float* __restrict__ var,
                                                 float* __restrict__ h, int residual) {
    int n = blockIdx.x;
    int d = threadIdx.x;
    int e0 = row_ptr[n], e1 = row_ptr[n + 1];
    float dn = dinv[n];
    float acc = t[(long)n * HID + d] * dn * dn;   // self loop
    for (int j = e0; j < e1; ++j)
        acc += t[(long)csr_src[j] * HID + d] * csr_w[j];
    float v = acc + b[d];
    v = (v - mean[d]) * rsqrtf(var[d] + BN_EPS) * gamma[d] + beta[d];
    v = fmaxf(v, 0.f);
    long idx = (long)n * HID + d;
    h[idx] = residual ? (h[idx] + v) : v;
}

// fused per-head GAT: max, single-pass denom + weighted gather, head-mean accumulate
// mode 0: agg = 0.25*att ; mode 1: agg += ; mode 2: h += agg + 0.25*att + gat_b
__global__ __launch_bounds__(128) void k_gat_agg(const float* __restrict__ t,
                                                 const int* __restrict__ row_ptr,
                                                 const int* __restrict__ csr_src,
                                                 const float* __restrict__ a_s,
                                                 const float* __restrict__ a_d,
                                                 const float* __restrict__ gat_b,
                                                 float* __restrict__ agg,
                                                 float* __restrict__ h, int mode) {
    int n = blockIdx.x;
    int d = threadIdx.x;
    int e0 = row_ptr[n], e1 = row_ptr[n + 1];
    float adn = a_d[n];
    float es = a_s[n] + adn;
    es = (es > 0.f) ? es : NEG_SLOPE * es;
    float m = es;
    for (int j = e0; j < e1; ++j) {
        float e = a_s[csr_src[j]] + adn;
        e = (e > 0.f) ? e : NEG_SLOPE * e;
        m = fmaxf(m, e);
    }
    float w0 = expf(es - m);
    float denom = w0;
    float acc = t[(long)n * HID + d] * w0;        // self loop
    for (int j = e0; j < e1; ++j) {
        int s = csr_src[j];
        float e = a_s[s] + adn;
        e = (e > 0.f) ? e : NEG_SLOPE * e;
        float w = expf(e - m);
        denom += w;
        acc += t[(long)s * HID + d] * w;
    }
    acc = 0.25f * acc / (denom + 1e-16f);
    long idx = (long)n * HID + d;
    if (mode == 0)      agg[idx] = acc;
    else if (mode == 1) agg[idx] += acc;
    else                h[idx] += agg[idx] + acc + gat_b[d];
}

// fused mean-pool + 3-layer classifier; one 128-thread block per graph.
// batch is sorted -> binary search the node range, no atomics anywhere.
__global__ __launch_bounds__(128) void k_pool_cls(const float* __restrict__ h,
                                                  const int* __restrict__ batch,
                                                  const float* __restrict__ c1W,
                                                  const float* __restrict__ c1b,
                                                  const float* __restrict__ c2W,
                                                  const float* __restrict__ c2b,
                                                  const float* __restrict__ c3W,
                                                  const float* __restrict__ c3b,
                                                  float* __restrict__ out) {
    int g = blockIdx.x;
    int tid = threadIdx.x;
    // lo = lower_bound(batch, g), hi = lower_bound(batch, g+1)
    int lo = 0, hb = NN;
    while (lo < hb) { int mid = (lo + hb) >> 1; if (batch[mid] < g) lo = mid + 1; else hb = mid; }
    int a = lo, b2 = NN;
    while (a < b2) { int mid = (a + b2) >> 1; if (batch[mid] < g + 1) a = mid + 1; else b2 = mid; }
    int hi = a;
    float s = 0.f;
    for (int n = lo; n < hi; ++n) s += h[(long)n * HID + tid];
    __shared__ float gbuf[HID];
    __shared__ float z1buf[64];
    __shared__ float z2buf[32];
    gbuf[tid] = s / fmaxf((float)(hi - lo), 1.f);
    __syncthreads();
    if (tid < 64) {
        float acc = c1b[tid];
        for (int d2 = 0; d2 < 128; ++d2) acc += gbuf[d2] * c1W[d2 * 64 + tid];
        z1buf[tid] = fmaxf(acc, 0.f);
    }
    __syncthreads();
    if (tid < 32) {
        float acc = c2b[tid];
        for (int d2 = 0; d2 < 64; ++d2) acc += z1buf[d2] * c2W[d2 * 32 + tid];
        z2buf[tid] = fmaxf(acc, 0.f);
    }
    __syncthreads();
    if (tid < 32) {
        float p = z2buf[tid] * c3W[tid];
#pragma unroll
        for (int off = 16; off > 0; off >>= 1) p += __shfl_down(p, off, 32);
        if (tid == 0) out[g] = p + c3b[0];
    }
}

extern "C" void kernel_launch(void* const* d_in, const int* in_sizes, int n_in,
                              void* d_out, int out_size, void* d_ws, size_t ws_size,
                              hipStream_t stream) {
    const float* x     = (const float*)d_in[0];
    const int*   ei    = (const int*)d_in[1];
    const int*   src   = ei;            // edge_index[0]
    const int*   dst   = ei + NE;       // edge_index[1]
    const int*   batch = (const int*)d_in[2];
    const float* gcn_W = (const float*)d_in[3];
    const float* gcn_b = (const float*)d_in[4];
    const float* bn_g  = (const float*)d_in[5];
    const float* bn_be = (const float*)d_in[6];
    const float* bn_m  = (const float*)d_in[7];
    const float* bn_v  = (const float*)d_in[8];
    const float* gat_W = (const float*)d_in[9];
    const float* att_s = (const float*)d_in[10];
    const float* att_d = (const float*)d_in[11];
    const float* gat_b = (const float*)d_in[12];
    const float* c1W = (const float*)d_in[13];
    const float* c1b = (const float*)d_in[14];
    const float* c2W = (const float*)d_in[15];
    const float* c2b = (const float*)d_in[16];
    const float* c3W = (const float*)d_in[17];
    const float* c3b = (const float*)d_in[18];
    float* out = (float*)d_out;

    float* ws = (float*)d_ws;
    size_t o = 0;
    float* dinv    = ws + o; o += NN;
    int*   cnt     = (int*)(ws + o); o += NN;              // count, then reused as fill
    int*   bsum    = (int*)(ws + o); o += 512;
    int*   row_ptr = (int*)(ws + o); o += NN + 1;
    int*   csr_src = (int*)(ws + o); o += NE;
    float* csr_w   = ws + o; o += NE;
    float* h       = ws + o; o += (size_t)NN * HID;
    float* t       = ws + o; o += (size_t)NN * HID;
    float* agg     = ws + o; o += (size_t)NN * HID;
    float* a_s     = ws + o; o += NN;
    float* a_d     = ws + o; o += NN;

    auto cdiv = [](long a, long b) { return (int)((a + b - 1) / b); };

    // ---- CSR build (by dst) + symmetric degree norm ----
    k_zero_i<<<cdiv(NN, 256), 256, 0, stream>>>(cnt, NN);
    k_count<<<cdiv(NE, 256), 256, 0, stream>>>(dst, cnt);
    k_dinv2<<<cdiv(NN, 256), 256, 0, stream>>>(cnt, dinv);
    k_bsum<<<NB_SCAN, 256, 0, stream>>>(cnt, bsum);
    k_bscan<<<1, 512, 0, stream>>>(bsum, row_ptr);
    k_rowptr<<<NB_SCAN, 256, 0, stream>>>(cnt, bsum, row_ptr);
    k_zero_i<<<cdiv(NN, 256), 256, 0, stream>>>(cnt, NN);  // reuse as fill
    k_csr<<<cdiv(NE, 256), 256, 0, stream>>>(src, dst, row_ptr, cnt, dinv, csr_src, csr_w);

    // ---- 3 GCN layers ----
    const float* hin = x;
    for (int L = 0; L < 3; ++L) {
        k_gemm128<<<cdiv(NN, 128), 512, 0, stream>>>(hin, gcn_W + (size_t)L * HID * HID, t,
                                                     NN, HID, 0, nullptr, nullptr, nullptr, nullptr);
        k_gcn_agg<<<NN, 128, 0, stream>>>(t, row_ptr, csr_src, csr_w, dinv,
                                          gcn_b + L * HID, bn_g + L * HID, bn_be + L * HID,
                                          bn_m + L * HID, bn_v + L * HID, h, L > 0);
        hin = h;
    }

    // ---- GAT: per head, fused scores (GEMM epilogue) + fused softmax-gather ----
    for (int hd = 0; hd < HEADS; ++hd) {
        k_gemm128<<<cdiv(NN, 128), 512, 0, stream>>>(h, gat_W, t, NN, HEADS * HID, hd * HID,
                                                     att_s + hd * HID, att_d + hd * HID, a_s, a_d);
        k_gat_agg<<<NN, 128, 0, stream>>>(t, row_ptr, csr_src, a_s, a_d, gat_b, agg, h,
                                          hd == 0 ? 0 : (hd == HEADS - 1 ? 2 : 1));
    }

    // ---- fused global mean pool + classifier ----
    k_pool_cls<<<NG, 128, 0, stream>>>(h, batch, c1W, c1b, c2W, c2b, c3W, c3b, out);
}

// Round 16
// 1150.799 us; speedup vs baseline: 1.1703x; 1.1703x over previous
//
#include <hip/hip_runtime.h>
#include <math.h>

#define NN 100000
#define NE 400000
#define HID 128
#define HEADS 4
#define NG 2000
#define BN_EPS 1e-5f
#define NEG_SLOPE 0.2f
#define NB_SCAN 391   // cdiv(NN,256)

__global__ void k_zero_i(int* __restrict__ p, int n) {
    int i = blockIdx.x * blockDim.x + threadIdx.x;
    if (i < n) p[i] = 0;
}

__global__ void k_count(const int* __restrict__ dst, int* __restrict__ cnt) {
    int e = blockIdx.x * blockDim.x + threadIdx.x;
    if (e < NE) atomicAdd(&cnt[dst[e]], 1);
}

__global__ void k_dinv2(const int* __restrict__ cnt, float* __restrict__ dinv) {
    int n = blockIdx.x * blockDim.x + threadIdx.x;
    if (n < NN) dinv[n] = rsqrtf((float)cnt[n] + 1.0f);   // +1 self loop
}

__global__ __launch_bounds__(256) void k_bsum(const int* __restrict__ cnt, int* __restrict__ bsum) {
    __shared__ int s[256];
    int tid = threadIdx.x;
    int n = blockIdx.x * 256 + tid;
    s[tid] = (n < NN) ? cnt[n] : 0;
    __syncthreads();
    for (int off = 128; off > 0; off >>= 1) {
        if (tid < off) s[tid] += s[tid + off];
        __syncthreads();
    }
    if (tid == 0) bsum[blockIdx.x] = s[0];
}

// exclusive scan of bsum[NB_SCAN] in one block; also set row_ptr[NN]=NE
__global__ __launch_bounds__(512) void k_bscan(int* __restrict__ bsum, int* __restrict__ row_ptr) {
    __shared__ int s[512];
    int tid = threadIdx.x;
    int v = (tid < NB_SCAN) ? bsum[tid] : 0;
    s[tid] = v;
    __syncthreads();
    for (int off = 1; off < 512; off <<= 1) {
        int t_ = (tid >= off) ? s[tid - off] : 0;
        __syncthreads();
        s[tid] += t_;
        __syncthreads();
    }
    if (tid < NB_SCAN) bsum[tid] = s[tid] - v;   // exclusive block offsets
    if (tid == 0) row_ptr[NN] = NE;
}

__global__ __launch_bounds__(256) void k_rowptr(const int* __restrict__ cnt, const int* __restrict__ boff,
                                                int* __restrict__ row_ptr) {
    __shared__ int s[256];
    int tid = threadIdx.x;
    int n = blockIdx.x * 256 + tid;
    int v = (n < NN) ? cnt[n] : 0;
    s[tid] = v;
    __syncthreads();
    for (int off = 1; off < 256; off <<= 1) {
        int t_ = (tid >= off) ? s[tid - off] : 0;
        __syncthreads();
        s[tid] += t_;
        __syncthreads();
    }
    if (n < NN) row_ptr[n] = boff[blockIdx.x] + s[tid] - v;
}

__global__ void k_csr(const int* __restrict__ src, const int* __restrict__ dst,
                      const int* __restrict__ row_ptr, int* __restrict__ fill,
                      const float* __restrict__ dinv,
                      int* __restrict__ csr_src, float* __restrict__ csr_w) {
    int e = blockIdx.x * blockDim.x + threadIdx.x;
    if (e >= NE) return;
    int s = src[e], d = dst[e];
    int pos = row_ptr[d] + atomicAdd(&fill[d], 1);
    csr_src[pos] = s;
    csr_w[pos] = dinv[s] * dinv[d];
}

// C[r, c] = sum_k A[r,k] * W[k*ldw + coffW + c]; optional fused att-score epilogue.
// 128x128 tile per 512-thread block; K=128 in two 64-halves. LDS 64KB.
__global__ __launch_bounds__(512) void k_gemm128(const float* __restrict__ A,
                                                 const float* __restrict__ W,
                                                 float* __restrict__ C,
                                                 int nrows, int ldw, int coffW,
                                                 const float* __restrict__ att_s,
                                                 const float* __restrict__ att_d,
                                                 float* __restrict__ as_out,
                                                 float* __restrict__ ad_out) {
    __shared__ float Ws[64][128];
    __shared__ float As[128][64];
    int tid = threadIdx.x;
    int row0 = blockIdx.x * 128;
    int c0 = (tid & 31) * 4;      // 4 consecutive output cols
    int r0 = (tid >> 5) * 8;      // 8 consecutive output rows
    float acc[8][4] = {};
    for (int kb = 0; kb < 2; ++kb) {
        __syncthreads();
        for (int i = tid; i < 2048; i += 512) {
            int k  = i >> 5;
            int c4 = (i & 31) * 4;
            *(float4*)&Ws[k][c4] =
                *(const float4*)&W[(long)(kb * 64 + k) * ldw + coffW + c4];
        }
        for (int i = tid; i < 2048; i += 512) {
            int r  = i >> 4;
            int k4 = (i & 15) * 4;
            int gr = row0 + r;
            float4 v = (gr < nrows)
                ? *(const float4*)&A[(long)gr * 128 + kb * 64 + k4]
                : make_float4(0.f, 0.f, 0.f, 0.f);
            *(float4*)&As[r][k4] = v;
        }
        __syncthreads();
        for (int k4 = 0; k4 < 64; k4 += 4) {
            float4 a4[8];
#pragma unroll
            for (int j = 0; j < 8; ++j) a4[j] = *(const float4*)&As[r0 + j][k4];
#pragma unroll
            for (int i = 0; i < 4; ++i) {
                float4 wv = *(const float4*)&Ws[k4 + i][c0];
#pragma unroll
                for (int j = 0; j < 8; ++j) {
                    float a = (i == 0) ? a4[j].x : (i == 1) ? a4[j].y : (i == 2) ? a4[j].z : a4[j].w;
                    acc[j][0] += a * wv.x;
                    acc[j][1] += a * wv.y;
                    acc[j][2] += a * wv.z;
                    acc[j][3] += a * wv.w;
                }
            }
        }
    }
#pragma unroll
    for (int j = 0; j < 8; ++j) {
        int gr = row0 + r0 + j;
        if (gr < nrows)
            *(float4*)&C[(long)gr * 128 + c0] =
                make_float4(acc[j][0], acc[j][1], acc[j][2], acc[j][3]);
    }
    if (att_s) {
#pragma unroll
        for (int j = 0; j < 8; ++j) {
            float ps = acc[j][0] * att_s[c0] + acc[j][1] * att_s[c0 + 1]
                     + acc[j][2] * att_s[c0 + 2] + acc[j][3] * att_s[c0 + 3];
            float pd = acc[j][0] * att_d[c0] + acc[j][1] * att_d[c0 + 1]
                     + acc[j][2] * att_d[c0 + 2] + acc[j][3] * att_d[c0 + 3];
#pragma unroll
            for (int off = 16; off > 0; off >>= 1) {
                ps += __shfl_down(ps, off, 32);
                pd += __shfl_down(pd, off, 32);
            }
            int gr = row0 + r0 + j;
            if ((tid & 31) == 0 && gr < nrows) { as_out[gr] = ps; ad_out[gr] = pd; }
        }
    }
}

// fused CSR gather + bias + BN + ReLU + residual; 32 lanes x float4 per node, 4 nodes/block
__global__ __launch_bounds__(128) void k_gcn_agg(const float* __restrict__ t,
                                                 const int* __restrict__ row_ptr,
                                                 const int* __restrict__ csr_src,
                                                 const float* __restrict__ csr_w,
                                                 const float* __restrict__ dinv,
                                                 const float* __restrict__ b,
                                                 const float* __restrict__ gamma,
                                                 const float* __restrict__ beta,
                                                 const float* __restrict__ mean,
                                                 const float* __restrict__ var,
                                                 float* __restrict__ h, int residual) {
    int node = blockIdx.x * 4 + (threadIdx.x >> 5);
    if (node >= NN) return;
    int c = (threadIdx.x & 31) * 4;
    int e0 = row_ptr[node], e1 = row_ptr[node + 1];
    float dn = dinv[node];
    float sw = dn * dn;
    float4 acc = *(const float4*)&t[(long)node * HID + c];
    acc.x *= sw; acc.y *= sw; acc.z *= sw; acc.w *= sw;
    for (int j = e0; j < e1; ++j) {
        int s = csr_src[j];
        float w = csr_w[j];
        float4 v = *(const float4*)&t[(long)s * HID + c];
        acc.x += v.x * w; acc.y += v.y * w; acc.z += v.z * w; acc.w += v.w * w;
    }
    float4 bb = *(const float4*)&b[c];
    float4 mm = *(const float4*)&mean[c];
    float4 vv = *(const float4*)&var[c];
    float4 gg = *(const float4*)&gamma[c];
    float4 be = *(const float4*)&beta[c];
    float4 r;
    r.x = fmaxf((acc.x + bb.x - mm.x) * rsqrtf(vv.x + BN_EPS) * gg.x + be.x, 0.f);
    r.y = fmaxf((acc.y + bb.y - mm.y) * rsqrtf(vv.y + BN_EPS) * gg.y + be.y, 0.f);
    r.z = fmaxf((acc.z + bb.z - mm.z) * rsqrtf(vv.z + BN_EPS) * gg.z + be.z, 0.f);
    r.w = fmaxf((acc.w + bb.w - mm.w) * rsqrtf(vv.w + BN_EPS) * gg.w + be.w, 0.f);
    long idx = (long)node * HID + c;
    if (residual) {
        float4 hp = *(const float4*)&h[idx];
        r.x += hp.x; r.y += hp.y; r.z += hp.z; r.w += hp.w;
    }
    *(float4*)&h[idx] = r;
}

// per-node softmax weights: alpha[j] per edge, selfw[n] for the self loop (1 thread/node)
__global__ void k_gat_w(const int* __restrict__ row_ptr, const int* __restrict__ csr_src,
                        const float* __restrict__ a_s, const float* __restrict__ a_d,
                        float* __restrict__ alpha, float* __restrict__ selfw) {
    int n = blockIdx.x * blockDim.x + threadIdx.x;
    if (n >= NN) return;
    int e0 = row_ptr[n], e1 = row_ptr[n + 1];
    float adn = a_d[n];
    float es = a_s[n] + adn;
    es = (es > 0.f) ? es : NEG_SLOPE * es;
    float m = es;
    for (int j = e0; j < e1; ++j) {
        float e = a_s[csr_src[j]] + adn;
        e = (e > 0.f) ? e : NEG_SLOPE * e;
        m = fmaxf(m, e);
    }
    float w0 = expf(es - m);
    float denom = w0;
    for (int j = e0; j < e1; ++j) {
        float e = a_s[csr_src[j]] + adn;
        e = (e > 0.f) ? e : NEG_SLOPE * e;
        float w = expf(e - m);
        alpha[j] = w;
        denom += w;
    }
    float inv = 1.f / (denom + 1e-16f);
    selfw[n] = w0 * inv;
    for (int j = e0; j < e1; ++j) alpha[j] *= inv;
}

// pure weighted gather; 32 lanes x float4 per node, 4 nodes/block
// mode 0: agg = 0.25*att ; mode 1: agg += ; mode 2: h += agg + 0.25*att + gat_b
__global__ __launch_bounds__(128) void k_gat_agg(const float* __restrict__ t,
                                                 const int* __restrict__ row_ptr,
                                                 const int* __restrict__ csr_src,
                                                 const float* __restrict__ alpha,
                                                 const float* __restrict__ selfw,
                                                 const float* __restrict__ gat_b,
                                                 float* __restrict__ agg,
                                                 float* __restrict__ h, int mode) {
    int node = blockIdx.x * 4 + (threadIdx.x >> 5);
    if (node >= NN) return;
    int c = (threadIdx.x & 31) * 4;
    int e0 = row_ptr[node], e1 = row_ptr[node + 1];
    float sw = selfw[node];
    float4 acc = *(const float4*)&t[(long)node * HID + c];
    acc.x *= sw; acc.y *= sw; acc.z *= sw; acc.w *= sw;
    for (int j = e0; j < e1; ++j) {
        int s = csr_src[j];
        float w = alpha[j];
        float4 v = *(const float4*)&t[(long)s * HID + c];
        acc.x += v.x * w; acc.y += v.y * w; acc.z += v.z * w; acc.w += v.w * w;
    }
    acc.x *= 0.25f; acc.y *= 0.25f; acc.z *= 0.25f; acc.w *= 0.25f;
    long idx = (long)node * HID + c;
    if (mode == 0) {
        *(float4*)&agg[idx] = acc;
    } else if (mode == 1) {
        float4 p = *(const float4*)&agg[idx];
        p.x += acc.x; p.y += acc.y; p.z += acc.z; p.w += acc.w;
        *(float4*)&agg[idx] = p;
    } else {
        float4 p = *(const float4*)&agg[idx];
        float4 hp = *(const float4*)&h[idx];
        float4 gb = *(const float4*)&gat_b[c];
        hp.x += p.x + acc.x + gb.x;
        hp.y += p.y + acc.y + gb.y;
        hp.z += p.z + acc.z + gb.z;
        hp.w += p.w + acc.w + gb.w;
        *(float4*)&h[idx] = hp;
    }
}

// fused mean-pool + 3-layer classifier; one 128-thread block per graph.
__global__ __launch_bounds__(128) void k_pool_cls(const float* __restrict__ h,
                                                  const int* __restrict__ batch,
                                                  const float* __restrict__ c1W,
                                                  const float* __restrict__ c1b,
                                                  const float* __restrict__ c2W,
                                                  const float* __restrict__ c2b,
                                                  const float* __restrict__ c3W,
                                                  const float* __restrict__ c3b,
                                                  float* __restrict__ out) {
    int g = blockIdx.x;
    int tid = threadIdx.x;
    int lo = 0, hb = NN;
    while (lo < hb) { int mid = (lo + hb) >> 1; if (batch[mid] < g) lo = mid + 1; else hb = mid; }
    int a = lo, b2 = NN;
    while (a < b2) { int mid = (a + b2) >> 1; if (batch[mid] < g + 1) a = mid + 1; else b2 = mid; }
    int hi = a;
    float s = 0.f;
    for (int n = lo; n < hi; ++n) s += h[(long)n * HID + tid];
    __shared__ float gbuf[HID];
    __shared__ float z1buf[64];
    __shared__ float z2buf[32];
    gbuf[tid] = s / fmaxf((float)(hi - lo), 1.f);
    __syncthreads();
    if (tid < 64) {
        float acc = c1b[tid];
        for (int d2 = 0; d2 < 128; ++d2) acc += gbuf[d2] * c1W[d2 * 64 + tid];
        z1buf[tid] = fmaxf(acc, 0.f);
    }
    __syncthreads();
    if (tid < 32) {
        float acc = c2b[tid];
        for (int d2 = 0; d2 < 64; ++d2) acc += z1buf[d2] * c2W[d2 * 32 + tid];
        z2buf[tid] = fmaxf(acc, 0.f);
    }
    __syncthreads();
    if (tid < 32) {
        float p = z2buf[tid] * c3W[tid];
#pragma unroll
        for (int off = 16; off > 0; off >>= 1) p += __shfl_down(p, off, 32);
        if (tid == 0) out[g] = p + c3b[0];
    }
}

extern "C" void kernel_launch(void* const* d_in, const int* in_sizes, int n_in,
                              void* d_out, int out_size, void* d_ws, size_t ws_size,
                              hipStream_t stream) {
    const float* x     = (const float*)d_in[0];
    const int*   ei    = (const int*)d_in[1];
    const int*   src   = ei;            // edge_index[0]
    const int*   dst   = ei + NE;       // edge_index[1]
    const int*   batch = (const int*)d_in[2];
    const float* gcn_W = (const float*)d_in[3];
    const float* gcn_b = (const float*)d_in[4];
    const float* bn_g  = (const float*)d_in[5];
    const float* bn_be = (const float*)d_in[6];
    const float* bn_m  = (const float*)d_in[7];
    const float* bn_v  = (const float*)d_in[8];
    const float* gat_W = (const float*)d_in[9];
    const float* att_s = (const float*)d_in[10];
    const float* att_d = (const float*)d_in[11];
    const float* gat_b = (const float*)d_in[12];
    const float* c1W = (const float*)d_in[13];
    const float* c1b = (const float*)d_in[14];
    const float* c2W = (const float*)d_in[15];
    const float* c2b = (const float*)d_in[16];
    const float* c3W = (const float*)d_in[17];
    const float* c3b = (const float*)d_in[18];
    float* out = (float*)d_out;

    float* ws = (float*)d_ws;
    size_t o = 0;
    float* dinv    = ws + o; o += NN;
    int*   cnt     = (int*)(ws + o); o += NN;              // count, then reused as fill
    int*   bsum    = (int*)(ws + o); o += 512;
    int*   row_ptr = (int*)(ws + o); o += NN + 4;          // padded -> keeps h/t/agg 16B-aligned
    int*   csr_src = (int*)(ws + o); o += NE;
    float* csr_w   = ws + o; o += NE;
    float* h       = ws + o; o += (size_t)NN * HID;
    float* t       = ws + o; o += (size_t)NN * HID;
    float* agg     = ws + o; o += (size_t)NN * HID;
    float* a_s     = ws + o; o += NN;
    float* a_d     = ws + o; o += NN;
    float* alpha   = ws + o; o += NE;
    float* selfw   = ws + o; o += NN;

    auto cdiv = [](long a, long b) { return (int)((a + b - 1) / b); };

    // ---- CSR build (by dst) + symmetric degree norm ----
    k_zero_i<<<cdiv(NN, 256), 256, 0, stream>>>(cnt, NN);
    k_count<<<cdiv(NE, 256), 256, 0, stream>>>(dst, cnt);
    k_dinv2<<<cdiv(NN, 256), 256, 0, stream>>>(cnt, dinv);
    k_bsum<<<NB_SCAN, 256, 0, stream>>>(cnt, bsum);
    k_bscan<<<1, 512, 0, stream>>>(bsum, row_ptr);
    k_rowptr<<<NB_SCAN, 256, 0, stream>>>(cnt, bsum, row_ptr);
    k_zero_i<<<cdiv(NN, 256), 256, 0, stream>>>(cnt, NN);  // reuse as fill
    k_csr<<<cdiv(NE, 256), 256, 0, stream>>>(src, dst, row_ptr, cnt, dinv, csr_src, csr_w);

    // ---- 3 GCN layers ----
    const float* hin = x;
    for (int L = 0; L < 3; ++L) {
        k_gemm128<<<cdiv(NN, 128), 512, 0, stream>>>(hin, gcn_W + (size_t)L * HID * HID, t,
                                                     NN, HID, 0, nullptr, nullptr, nullptr, nullptr);
        k_gcn_agg<<<cdiv(NN, 4), 128, 0, stream>>>(t, row_ptr, csr_src, csr_w, dinv,
                                          gcn_b + L * HID, bn_g + L * HID, bn_be + L * HID,
                                          bn_m + L * HID, bn_v + L * HID, h, L > 0);
        hin = h;
    }

    // ---- GAT: per head: GEMM(+scores) -> per-node softmax weights -> weighted gather ----
    for (int hd = 0; hd < HEADS; ++hd) {
        k_gemm128<<<cdiv(NN, 128), 512, 0, stream>>>(h, gat_W, t, NN, HEADS * HID, hd * HID,
                                                     att_s + hd * HID, att_d + hd * HID, a_s, a_d);
        k_gat_w<<<cdiv(NN, 256), 256, 0, stream>>>(row_ptr, csr_src, a_s, a_d, alpha, selfw);
        k_gat_agg<<<cdiv(NN, 4), 128, 0, stream>>>(t, row_ptr, csr_src, alpha, selfw, gat_b, agg, h,
                                          hd == 0 ? 0 : (hd == HEADS - 1 ? 2 : 1));
    }

    // ---- fused global mean pool + classifier ----
    k_pool_cls<<<NG, 128, 0, stream>>>(h, batch, c1W, c1b, c2W, c2b, c3W, c3b, out);
}